// Round 1
// baseline (472.460 us; speedup 1.0000x reference)
//
#include <hip/hip_runtime.h>
#include <stdint.h>

typedef unsigned short u16;
typedef __attribute__((ext_vector_type(8))) short bh8;   // 8 bf16 = 4 VGPR
typedef __attribute__((ext_vector_type(4))) float f4;    // MFMA acc

#define LOG2E 1.44269504088896f

__device__ inline u16 f2bf(float f) {
  union { float f; uint32_t u; } c; c.f = f;
  uint32_t u = c.u;
  return (u16)((u + 0x7fffu + ((u >> 16) & 1u)) >> 16);  // RNE
}

__device__ inline float fast_exp2(float x) {
#if __has_builtin(__builtin_amdgcn_exp2f)
  return __builtin_amdgcn_exp2f(x);
#else
  return exp2f(x);
#endif
}

#if __has_builtin(__builtin_amdgcn_global_load_lds)
#define GLD16(gp, lp) __builtin_amdgcn_global_load_lds( \
    (const __attribute__((address_space(1))) void*)(gp), \
    (__attribute__((address_space(3))) void*)(lp), 16, 0, 0)
#else
#define GLD16(gp, lp) do { *(bh8*)(lp) = *(const bh8*)(gp); } while (0)
#endif

// ---------------- convert / transpose ----------------

__global__ __launch_bounds__(256) void cvt_f32_bf16(const float* __restrict__ src,
                                                    u16* __restrict__ dst, int n4) {
  int i = blockIdx.x * 256 + threadIdx.x;
  if (i < n4) {
    float4 v = ((const float4*)src)[i];
    ushort4 o;
    o.x = f2bf(v.x); o.y = f2bf(v.y); o.z = f2bf(v.z); o.w = f2bf(v.w);
    ((ushort4*)dst)[i] = o;
  }
}

// src: K x N fp32 row-major -> dst: N x K bf16 row-major
__global__ __launch_bounds__(1024) void transpose_cvt(const float* __restrict__ src,
                                                      u16* __restrict__ dst, int K, int N) {
  __shared__ float tile[32][33];
  int n0 = blockIdx.x * 32, k0 = blockIdx.y * 32;
  int tx = threadIdx.x, ty = threadIdx.y;
  tile[ty][tx] = src[(size_t)(k0 + ty) * N + n0 + tx];
  __syncthreads();
  dst[(size_t)(n0 + ty) * K + k0 + tx] = f2bf(tile[tx][ty]);
}

// ---------------- GEMM mainloop (C = A @ Bt^T), 128x128 tile, BK=64 ----------------
// A: M x K bf16 row-major; Bt: N x K bf16 row-major.
// LDS layout: chunk (row, c) holds global chunk (row, c ^ (row&7)); 8 bf16 per chunk.
// This keeps global_load_lds's "uniform base + lane*16" dest rule AND makes the
// ds_read_b128 fragment reads conflict-free (2 lanes/bank).
__device__ inline void gemm_mainloop(const u16* __restrict__ A, const u16* __restrict__ Bt,
                                     int K, int m0, int n0,
                                     u16* As, u16* Bs, f4 acc[4][4]) {
  const int tid  = threadIdx.x;
  const int lane = tid & 63;
  const int quad = lane >> 4;
  const int ml   = lane & 15;
  const int wave = tid >> 6;
  const int wm   = (wave >> 1) * 64;
  const int wn   = (wave & 1) * 64;

#pragma unroll 1
  for (int k0 = 0; k0 < K; k0 += 64) {
#pragma unroll
    for (int r = 0; r < 4; ++r) {
      int chunk = r * 256 + tid;
      int row = chunk >> 3, cc = chunk & 7;
      int cg = cc ^ (row & 7);
      GLD16(A + (size_t)(m0 + row) * K + k0 + cg * 8, As + chunk * 8);
    }
#pragma unroll
    for (int r = 0; r < 4; ++r) {
      int chunk = r * 256 + tid;
      int row = chunk >> 3, cc = chunk & 7;
      int cg = cc ^ (row & 7);
      GLD16(Bt + (size_t)(n0 + row) * K + k0 + cg * 8, Bs + chunk * 8);
    }
    __syncthreads();
#pragma unroll
    for (int ks = 0; ks < 2; ++ks) {
      bh8 af[4], bfr[4];
      int cs = (ks * 4 + quad) ^ (ml & 7);  // row&7 == ml&7 (tile offsets are x16)
#pragma unroll
      for (int i = 0; i < 4; ++i) {
        int row = wm + i * 16 + ml;
        af[i] = *(const bh8*)(As + (row * 8 + cs) * 8);
      }
#pragma unroll
      for (int j = 0; j < 4; ++j) {
        int row = wn + j * 16 + ml;
        bfr[j] = *(const bh8*)(Bs + (row * 8 + cs) * 8);
      }
#pragma unroll
      for (int i = 0; i < 4; ++i)
#pragma unroll
        for (int j = 0; j < 4; ++j)
          acc[i][j] = __builtin_amdgcn_mfma_f32_16x16x32_bf16(af[i], bfr[j], acc[i][j], 0, 0, 0);
    }
    __syncthreads();
  }
}

// ---------------- GEMM1: qkv = x @ w_qkv + b, split into q/k/v_t ----------------
// q,k: [bh=64][l=2048][d=64] bf16 ; vt: [bh][d=64][l=2048] bf16 (transposed for PV B-frags)
__global__ __launch_bounds__(256) void gemm_qkv(const u16* __restrict__ xb,
                                                const u16* __restrict__ wqt,
                                                const float* __restrict__ bqkv,
                                                u16* __restrict__ q, u16* __restrict__ k,
                                                u16* __restrict__ vt) {
  __shared__ __align__(16) u16 smem[2 * 128 * 64];
  const f4 fzero = {0.f, 0.f, 0.f, 0.f};
  f4 acc[4][4];
#pragma unroll
  for (int i = 0; i < 4; ++i)
#pragma unroll
    for (int j = 0; j < 4; ++j) acc[i][j] = fzero;

  int m0 = blockIdx.y * 128, n0 = blockIdx.x * 128;
  gemm_mainloop(xb, wqt, 1024, m0, n0, smem, smem + 128 * 64, acc);

  const int lane = threadIdx.x & 63, wave = threadIdx.x >> 6;
  const int quad = lane >> 4, ml = lane & 15;
  const int wm = (wave >> 1) * 64, wn = (wave & 1) * 64;
#pragma unroll
  for (int j = 0; j < 4; ++j) {
    int nn = n0 + wn + j * 16 + ml;
    int sel = nn >> 10;            // 0=q 1=k 2=v (uniform per block)
    int h = (nn >> 6) & 15, d = nn & 63;
    float bias = bqkv[nn];
#pragma unroll
    for (int i = 0; i < 4; ++i) {
#pragma unroll
      for (int r = 0; r < 4; ++r) {
        int tok = m0 + wm + i * 16 + quad * 4 + r;
        int b = tok >> 11, l = tok & 2047;
        int bh = b * 16 + h;
        u16 bv = f2bf(acc[i][j][r] + bias);
        if (sel == 0)      q[((size_t)bh * 2048 + l) * 64 + d] = bv;
        else if (sel == 1) k[((size_t)bh * 2048 + l) * 64 + d] = bv;
        else               vt[((size_t)bh * 64 + d) * 2048 + l] = bv;
      }
    }
  }
}

// ---------------- GEMM2: out = o @ w_out + b_out (fp32 out) ----------------
__global__ __launch_bounds__(256) void gemm_out(const u16* __restrict__ ob,
                                                const u16* __restrict__ wot,
                                                const float* __restrict__ bout,
                                                float* __restrict__ out) {
  __shared__ __align__(16) u16 smem[2 * 128 * 64];
  const f4 fzero = {0.f, 0.f, 0.f, 0.f};
  f4 acc[4][4];
#pragma unroll
  for (int i = 0; i < 4; ++i)
#pragma unroll
    for (int j = 0; j < 4; ++j) acc[i][j] = fzero;

  int m0 = blockIdx.y * 128, n0 = blockIdx.x * 128;
  gemm_mainloop(ob, wot, 1024, m0, n0, smem, smem + 128 * 64, acc);

  const int lane = threadIdx.x & 63, wave = threadIdx.x >> 6;
  const int quad = lane >> 4, ml = lane & 15;
  const int wm = (wave >> 1) * 64, wn = (wave & 1) * 64;
#pragma unroll
  for (int j = 0; j < 4; ++j) {
    int nn = n0 + wn + j * 16 + ml;
    float bias = bout[nn];
#pragma unroll
    for (int i = 0; i < 4; ++i)
#pragma unroll
      for (int r = 0; r < 4; ++r) {
        int tok = m0 + wm + i * 16 + quad * 4 + r;
        out[(size_t)tok * 1024 + nn] = acc[i][j][r] + bias;
      }
  }
}

// ---------------- flash attention ----------------
// grid (16, 64): x = q-tile of 128 rows, y = bh. 4 waves, each owns 32 q-rows.
__global__ __launch_bounds__(256) void attn(const u16* __restrict__ q,
                                            const u16* __restrict__ k,
                                            const u16* __restrict__ vt,
                                            u16* __restrict__ o) {
  __shared__ __align__(16) u16 plds[4][2][16 * 64];  // per-wave, per-mtile P tiles (16KB)
  const int bh = blockIdx.y;
  const int b = bh >> 4, h = bh & 15;
  const int wave = threadIdx.x >> 6, lane = threadIdx.x & 63;
  const int quad = lane >> 4, ml = lane & 15;
  const int q0 = blockIdx.x * 128 + wave * 32;
  const u16* qp = q + (size_t)bh * 2048 * 64;
  const u16* kp = k + (size_t)bh * 2048 * 64;
  const u16* vp = vt + (size_t)bh * 64 * 2048;
  const f4 fzero = {0.f, 0.f, 0.f, 0.f};

  bh8 qf[2][2];
#pragma unroll
  for (int mt = 0; mt < 2; ++mt)
#pragma unroll
    for (int ks = 0; ks < 2; ++ks)
      qf[mt][ks] = *(const bh8*)&qp[(size_t)(q0 + mt * 16 + ml) * 64 + ks * 32 + quad * 8];

  f4 oacc[2][4];
  float mi[2][4], li[2][4];
#pragma unroll
  for (int mt = 0; mt < 2; ++mt) {
#pragma unroll
    for (int j = 0; j < 4; ++j) oacc[mt][j] = fzero;
#pragma unroll
    for (int r = 0; r < 4; ++r) { mi[mt][r] = -3.0e38f; li[mt][r] = 0.f; }
  }
  const float c1 = 0.125f * LOG2E;  // scale 1/sqrt(64), folded into exp2

#pragma unroll 1
  for (int kt = 0; kt < 2048; kt += 64) {
    // S = Q @ K^T  (raw scores)
    f4 s[2][4];
#pragma unroll
    for (int mt = 0; mt < 2; ++mt)
#pragma unroll
      for (int j = 0; j < 4; ++j) s[mt][j] = fzero;
#pragma unroll
    for (int ks = 0; ks < 2; ++ks) {
      bh8 kf[4];
#pragma unroll
      for (int j = 0; j < 4; ++j)
        kf[j] = *(const bh8*)&kp[(size_t)(kt + j * 16 + ml) * 64 + ks * 32 + quad * 8];
#pragma unroll
      for (int mt = 0; mt < 2; ++mt)
#pragma unroll
        for (int j = 0; j < 4; ++j)
          s[mt][j] = __builtin_amdgcn_mfma_f32_16x16x32_bf16(qf[mt][ks], kf[j], s[mt][j], 0, 0, 0);
    }
    // online softmax per mtile
#pragma unroll
    for (int mt = 0; mt < 2; ++mt) {
      float alpha[4], psum[4];
#pragma unroll
      for (int r = 0; r < 4; ++r) {
        float mx = fmaxf(fmaxf(s[mt][0][r], s[mt][1][r]), fmaxf(s[mt][2][r], s[mt][3][r]));
#pragma unroll
        for (int off = 1; off < 16; off <<= 1) mx = fmaxf(mx, __shfl_xor(mx, off, 64));
        float mnew = fmaxf(mi[mt][r], mx * 0.125f);
        alpha[r] = fast_exp2((mi[mt][r] - mnew) * LOG2E);
        mi[mt][r] = mnew;
        psum[r] = 0.f;
      }
#pragma unroll
      for (int j = 0; j < 4; ++j) {
#pragma unroll
        for (int r = 0; r < 4; ++r) {
          float p = fast_exp2(s[mt][j][r] * c1 - mi[mt][r] * LOG2E);
          psum[r] += p;
          int row = quad * 4 + r, col = j * 16 + ml;
          int cs = (col >> 3) ^ (row & 7);  // XOR swizzle, matches read below
          plds[wave][mt][row * 64 + cs * 8 + (col & 7)] = f2bf(p);
        }
      }
#pragma unroll
      for (int r = 0; r < 4; ++r) {
        float ps = psum[r];
#pragma unroll
        for (int off = 1; off < 16; off <<= 1) ps += __shfl_xor(ps, off, 64);
        li[mt][r] = li[mt][r] * alpha[r] + ps;
      }
#pragma unroll
      for (int j = 0; j < 4; ++j)
#pragma unroll
        for (int r = 0; r < 4; ++r) oacc[mt][j][r] *= alpha[r];
    }
    // O += P @ V
#pragma unroll
    for (int ks = 0; ks < 2; ++ks) {
      bh8 vf[4];
#pragma unroll
      for (int j = 0; j < 4; ++j)
        vf[j] = *(const bh8*)&vp[(size_t)(j * 16 + ml) * 2048 + kt + ks * 32 + quad * 8];
      int cs = (ks * 4 + quad) ^ (ml & 7);
#pragma unroll
      for (int mt = 0; mt < 2; ++mt) {
        bh8 pf = *(const bh8*)&plds[wave][mt][ml * 64 + cs * 8];
#pragma unroll
        for (int j = 0; j < 4; ++j)
          oacc[mt][j] = __builtin_amdgcn_mfma_f32_16x16x32_bf16(pf, vf[j], oacc[mt][j], 0, 0, 0);
      }
    }
  }
  // normalize + store o as (b, l, h, d) bf16
#pragma unroll
  for (int mt = 0; mt < 2; ++mt) {
    float inv[4];
#pragma unroll
    for (int r = 0; r < 4; ++r) inv[r] = 1.0f / li[mt][r];
#pragma unroll
    for (int j = 0; j < 4; ++j)
#pragma unroll
      for (int r = 0; r < 4; ++r) {
        int tl = q0 + mt * 16 + quad * 4 + r;
        int d = j * 16 + ml;
        o[(((size_t)b * 2048 + tl) * 16 + h) * 64 + d] = f2bf(oacc[mt][j][r] * inv[r]);
      }
  }
}

// ---------------- launch ----------------

extern "C" void kernel_launch(void* const* d_in, const int* in_sizes, int n_in,
                              void* d_out, int out_size, void* d_ws, size_t ws_size,
                              hipStream_t stream) {
  const float* x     = (const float*)d_in[0];
  const float* w_qkv = (const float*)d_in[1];
  const float* b_qkv = (const float*)d_in[2];
  const float* w_out = (const float*)d_in[3];
  const float* b_out = (const float*)d_in[4];
  float* out = (float*)d_out;

  u16* ws  = (u16*)d_ws;
  u16* xb  = ws;                                  // 8192*1024
  u16* wqt = xb + (size_t)8192 * 1024;            // 3072*1024
  u16* wot = wqt + (size_t)3072 * 1024;           // 1024*1024
  u16* qb  = wot + (size_t)1024 * 1024;           // 64*2048*64
  u16* kb  = qb + (size_t)64 * 2048 * 64;
  u16* vtb = kb + (size_t)64 * 2048 * 64;
  u16* ob  = xb;  // reuse x_bf16 region after gemm_qkv is done with it

  cvt_f32_bf16<<<8192, 256, 0, stream>>>(x, xb, 8192 * 1024 / 4);
  transpose_cvt<<<dim3(96, 32), dim3(32, 32), 0, stream>>>(w_qkv, wqt, 1024, 3072);
  transpose_cvt<<<dim3(32, 32), dim3(32, 32), 0, stream>>>(w_out, wot, 1024, 1024);
  gemm_qkv<<<dim3(24, 64), 256, 0, stream>>>(xb, wqt, b_qkv, qb, kb, vtb);
  attn<<<dim3(16, 64), 256, 0, stream>>>(qb, kb, vtb, ob);
  gemm_out<<<dim3(8, 64), 256, 0, stream>>>(ob, wot, b_out, out);
}